// Round 2
// baseline (6295.096 us; speedup 1.0000x reference)
//
#include <hip/hip_runtime.h>
#include <math.h>

// LotkaVolterra neural-SDE rollout. P=4096 paths, H=256, 100 sequential steps.
// Per-path-independent recurrence: 1 block = 16 paths, persistent over steps.
// R1 change: 256 -> 1024 threads/block (16 waves/CU vs 4) to hide L2/LDS
// latency. Thread tile 1 path x 4 cols (pg=tid&15, jg=tid>>4). Per-block L2
// weight traffic unchanged (256KB/layer/step).

#define PP 4096
#define HH 256
#define LT 100
#define PB 16          // paths per block
#define SS 260         // padded LDS row stride (mod 32 == 4 -> free 2-way conflicts only)

__device__ __forceinline__ float softplus_f(float x) {
    return fmaxf(x, 0.0f) + log1pf(expf(-fabsf(x)));
}

__device__ __forceinline__ float4 ldg4(const float* p) { return *(const float4*)p; }

// 256->256 dense + bias (+optional relu), 1 path x 4 cols per thread.
template <bool RELU>
__device__ __forceinline__ void dense256(const float* __restrict__ W,
                                         const float4 bias,
                                         const float (&hin)[PB][SS],
                                         float (&hout)[PB][SS],
                                         int pg, int jg) {
    const float* wp = W + 4 * jg;
    float a0 = bias.x, a1 = bias.y, a2 = bias.z, a3 = bias.w;
    // software-pipeline: weights + h one 4-k chunk ahead
    float4 w0 = ldg4(wp + 0 * HH), w1 = ldg4(wp + 1 * HH),
           w2 = ldg4(wp + 2 * HH), w3 = ldg4(wp + 3 * HH);
    float4 h = *(const float4*)&hin[pg][0];
#pragma unroll 1
    for (int kc = 0; kc < 63; ++kc) {
        const int k = kc * 4;
        float4 n0 = ldg4(wp + (k + 4) * HH), n1 = ldg4(wp + (k + 5) * HH),
               n2 = ldg4(wp + (k + 6) * HH), n3 = ldg4(wp + (k + 7) * HH);
        float4 hn = *(const float4*)&hin[pg][k + 4];
        a0 = fmaf(h.x, w0.x, a0); a1 = fmaf(h.x, w0.y, a1);
        a2 = fmaf(h.x, w0.z, a2); a3 = fmaf(h.x, w0.w, a3);
        a0 = fmaf(h.y, w1.x, a0); a1 = fmaf(h.y, w1.y, a1);
        a2 = fmaf(h.y, w1.z, a2); a3 = fmaf(h.y, w1.w, a3);
        a0 = fmaf(h.z, w2.x, a0); a1 = fmaf(h.z, w2.y, a1);
        a2 = fmaf(h.z, w2.z, a2); a3 = fmaf(h.z, w2.w, a3);
        a0 = fmaf(h.w, w3.x, a0); a1 = fmaf(h.w, w3.y, a1);
        a2 = fmaf(h.w, w3.z, a2); a3 = fmaf(h.w, w3.w, a3);
        w0 = n0; w1 = n1; w2 = n2; w3 = n3; h = hn;
    }
    a0 = fmaf(h.x, w0.x, a0); a1 = fmaf(h.x, w0.y, a1);
    a2 = fmaf(h.x, w0.z, a2); a3 = fmaf(h.x, w0.w, a3);
    a0 = fmaf(h.y, w1.x, a0); a1 = fmaf(h.y, w1.y, a1);
    a2 = fmaf(h.y, w1.z, a2); a3 = fmaf(h.y, w1.w, a3);
    a0 = fmaf(h.z, w2.x, a0); a1 = fmaf(h.z, w2.y, a1);
    a2 = fmaf(h.z, w2.z, a2); a3 = fmaf(h.z, w2.w, a3);
    a0 = fmaf(h.w, w3.x, a0); a1 = fmaf(h.w, w3.y, a1);
    a2 = fmaf(h.w, w3.z, a2); a3 = fmaf(h.w, w3.w, a3);
    float4 o;
    if (RELU) {
        o.x = fmaxf(a0, 0.0f); o.y = fmaxf(a1, 0.0f);
        o.z = fmaxf(a2, 0.0f); o.w = fmaxf(a3, 0.0f);
    } else {
        o.x = a0; o.y = a1; o.z = a2; o.w = a3;
    }
    *(float4*)&hout[pg][4 * jg] = o;
}

// 8->256 dense + bias + relu, 1 path x 4 cols per thread.
__device__ __forceinline__ void dense8(const float* __restrict__ W0,
                                       const float4 bias,
                                       const float (&x)[PB][8],
                                       float (&hout)[PB][SS],
                                       int pg, int jg) {
    const float* wp = W0 + 4 * jg;
    float4 xa = *(const float4*)&x[pg][0];
    float4 xb = *(const float4*)&x[pg][4];
    float a0 = bias.x, a1 = bias.y, a2 = bias.z, a3 = bias.w;
    float4 w;
    w = ldg4(wp + 0 * HH);
    a0 = fmaf(xa.x, w.x, a0); a1 = fmaf(xa.x, w.y, a1); a2 = fmaf(xa.x, w.z, a2); a3 = fmaf(xa.x, w.w, a3);
    w = ldg4(wp + 1 * HH);
    a0 = fmaf(xa.y, w.x, a0); a1 = fmaf(xa.y, w.y, a1); a2 = fmaf(xa.y, w.z, a2); a3 = fmaf(xa.y, w.w, a3);
    w = ldg4(wp + 2 * HH);
    a0 = fmaf(xa.z, w.x, a0); a1 = fmaf(xa.z, w.y, a1); a2 = fmaf(xa.z, w.z, a2); a3 = fmaf(xa.z, w.w, a3);
    w = ldg4(wp + 3 * HH);
    a0 = fmaf(xa.w, w.x, a0); a1 = fmaf(xa.w, w.y, a1); a2 = fmaf(xa.w, w.z, a2); a3 = fmaf(xa.w, w.w, a3);
    w = ldg4(wp + 4 * HH);
    a0 = fmaf(xb.x, w.x, a0); a1 = fmaf(xb.x, w.y, a1); a2 = fmaf(xb.x, w.z, a2); a3 = fmaf(xb.x, w.w, a3);
    w = ldg4(wp + 5 * HH);
    a0 = fmaf(xb.y, w.x, a0); a1 = fmaf(xb.y, w.y, a1); a2 = fmaf(xb.y, w.z, a2); a3 = fmaf(xb.y, w.w, a3);
    w = ldg4(wp + 6 * HH);
    a0 = fmaf(xb.z, w.x, a0); a1 = fmaf(xb.z, w.y, a1); a2 = fmaf(xb.z, w.z, a2); a3 = fmaf(xb.z, w.w, a3);
    w = ldg4(wp + 7 * HH);
    a0 = fmaf(xb.w, w.x, a0); a1 = fmaf(xb.w, w.y, a1); a2 = fmaf(xb.w, w.z, a2); a3 = fmaf(xb.w, w.w, a3);
    float4 o;
    o.x = fmaxf(a0, 0.0f); o.y = fmaxf(a1, 0.0f);
    o.z = fmaxf(a2, 0.0f); o.w = fmaxf(a3, 0.0f);
    *(float4*)&hout[pg][4 * jg] = o;
}

__global__ __launch_bounds__(1024, 1)
void lv_kernel(const float* __restrict__ W0, const float* __restrict__ b0,
               const float* __restrict__ W1, const float* __restrict__ b1,
               const float* __restrict__ W2, const float* __restrict__ b2,
               const float* __restrict__ W3, const float* __restrict__ b3,
               const float* __restrict__ obs_init, const float* __restrict__ feature_init,
               const float* __restrict__ tn_store, const float* __restrict__ x1_store,
               const float* __restrict__ x2_store, const float* __restrict__ path_seed,
               float* __restrict__ out) {
    __shared__ float hA[PB][SS];
    __shared__ float hB[PB][SS];
    __shared__ float xs[PB][8];
    __shared__ float o3[PB][5];
    __shared__ float st[PB][2];

    const int tid = threadIdx.x;
    const int pg = tid & 15;       // path 0..15
    const int jg = tid >> 4;       // col group 0..63 -> cols 4*jg..4*jg+3
    const int pbase = blockIdx.x * PB;

    const float DTf = 0.1f;
    const float SQ = 0.31622776601683794f;  // sqrt(0.1)

    float* __restrict__ path_out = out;                          // (P, 2, 101)
    float* __restrict__ mu_out = out + PP * 2 * (LT + 1);        // (P*100, 2)
    float* __restrict__ sg_out = mu_out + PP * LT * 2;           // (P*100, 2, 2)

    float tval = feature_init[0];  // t0 = feature_init[0,0,0]

    // hoist biases (invariant across steps)
    const float4 bv0 = ldg4(b0 + 4 * jg);
    const float4 bv1 = ldg4(b1 + 4 * jg);
    const float4 bv2 = ldg4(b2 + 4 * jg);

    if (tid < PB) {
        const int p = tid, gp = pbase + p;
        st[p][0] = obs_init[gp * 2 + 0];
        st[p][1] = obs_init[gp * 2 + 1];
    }

    for (int t = 0; t < LT; ++t) {
        if (t > 0) tval += DTf;  // matches ref's sequential fp32 accumulation
        if (tid < PB) {
            const int p = tid, gp = pbase + p;
            xs[p][0] = st[p][0];
            xs[p][1] = st[p][1];
            if (t == 0) {
#pragma unroll
                for (int f = 0; f < 6; ++f) xs[p][2 + f] = feature_init[gp * 6 + f];
                path_out[gp * 202 + 0] = obs_init[gp * 2 + 0];
                path_out[gp * 202 + 101] = obs_init[gp * 2 + 1];
            } else {
                const float tn = tn_store[t - 1];
                const float a1 = x1_store[t - 1];
                const float a2 = x2_store[t - 1];
                xs[p][2] = tval; xs[p][3] = tn;
                xs[p][4] = a1;   xs[p][5] = a2;
                xs[p][6] = a1;   xs[p][7] = a2;
            }
        }
        __syncthreads();

        dense8(W0, bv0, xs, hA, pg, jg);          // h0 = relu(x @ W0 + b0)
        __syncthreads();
        dense256<true>(W1, bv1, hA, hB, pg, jg);  // h1 = relu(h0 @ W1 + b1)
        __syncthreads();
        dense256<true>(W2, bv2, hB, hA, pg, jg);  // h2 = relu(h1 @ W2 + b2)
        __syncthreads();

        // layer 3: 256->5, threads 0..79, one (path, col) each
        if (tid < 80) {
            const int p = tid / 5, c = tid % 5;
            float acc = b3[c];
            const float* hr = hA[p];
#pragma unroll 4
            for (int k4 = 0; k4 < 64; ++k4) {
                float4 h = *(const float4*)&hr[4 * k4];
                const float* w = W3 + (4 * k4) * 5 + c;
                acc = fmaf(h.x, w[0], acc);
                acc = fmaf(h.y, w[5], acc);
                acc = fmaf(h.z, w[10], acc);
                acc = fmaf(h.w, w[15], acc);
            }
            o3[p][c] = acc;
        }
        __syncthreads();

        // sampling + stores: threads 0..15, one path each.
        // No trailing barrier needed: st/o3 are read+written only by tid<16,
        // and next step's hA writes are gated by the sync after xs-build.
        if (tid < PB) {
            const int p = tid, gp = pbase + p;
            const float mu0 = o3[p][0];
            const float mu1 = o3[p][1];
            const float s11 = softplus_f(o3[p][2]);
            const float s21 = o3[p][3];
            const float s22 = softplus_f(o3[p][4]);
            const float e0 = path_seed[(size_t)t * PP * 2 + gp * 2 + 0];
            const float e1 = path_seed[(size_t)t * PP * 2 + gp * 2 + 1];
            const float n0 = softplus_f(st[p][0] + DTf * mu0 + SQ * (s11 * e0));
            const float n1 = softplus_f(st[p][1] + DTf * mu1 + SQ * (s21 * e0 + s22 * e1));
            st[p][0] = n0;
            st[p][1] = n1;
            path_out[gp * 202 + (t + 1)] = n0;
            path_out[gp * 202 + 101 + (t + 1)] = n1;
            mu_out[gp * 200 + t * 2 + 0] = mu0;
            mu_out[gp * 200 + t * 2 + 1] = mu1;
            sg_out[gp * 400 + t * 4 + 0] = s11;
            sg_out[gp * 400 + t * 4 + 1] = 0.0f;
            sg_out[gp * 400 + t * 4 + 2] = s21;
            sg_out[gp * 400 + t * 4 + 3] = s22;
        }
        __syncthreads();  // hA/hB reuse + st visibility for next iteration
    }
}

extern "C" void kernel_launch(void* const* d_in, const int* in_sizes, int n_in,
                              void* d_out, int out_size, void* d_ws, size_t ws_size,
                              hipStream_t stream) {
    (void)in_sizes; (void)n_in; (void)out_size; (void)d_ws; (void)ws_size;
    lv_kernel<<<PP / PB, 1024, 0, stream>>>(
        (const float*)d_in[0], (const float*)d_in[1],
        (const float*)d_in[2], (const float*)d_in[3],
        (const float*)d_in[4], (const float*)d_in[5],
        (const float*)d_in[6], (const float*)d_in[7],
        (const float*)d_in[8], (const float*)d_in[9],
        (const float*)d_in[10], (const float*)d_in[11],
        (const float*)d_in[12], (const float*)d_in[13],
        (float*)d_out);
}

// Round 3
// 4641.817 us; speedup vs baseline: 1.3562x; 1.3562x over previous
//
#include <hip/hip_runtime.h>
#include <math.h>

// LotkaVolterra neural-SDE rollout. P=4096, H=256, 100 sequential steps.
// R3: PB=8 paths/block, grid 512 (2 blocks/CU), 256 thr, tile 2 paths x 4 cols.
// Wave = 16 distinct jg x 4 pg -> 256B coalesced weight wave-loads (R0 geometry),
// 1024 VMEM instrs/block-layer. Register software pipeline depth 3 on both
// weights (global/L2) and h (LDS) to cover ~400cyc latency at 2 waves/SIMD.
// W3 transposed into LDS once (kills per-step strided gather in layer 3).

#define PP 4096
#define HH 256
#define LT 100
#define PB 8           // paths per block
#define SS 260         // padded LDS row stride (mod 32 == 4 -> free 2-way conflicts only)

__device__ __forceinline__ float softplus_f(float x) {
    return fmaxf(x, 0.0f) + log1pf(expf(-fabsf(x)));
}

__device__ __forceinline__ float4 ldg4(const float* p) { return *(const float4*)p; }

// 256->256 dense + bias (+optional relu). Tile: 2 paths x 4 cols per thread.
// Software pipeline: 4-stage rotating register buffers, load 3 chunks ahead.
template <bool RELU>
__device__ __forceinline__ void dense256(const float* __restrict__ W,
                                         const float4 bias,
                                         const float (&hin)[PB][SS],
                                         float (&hout)[PB][SS],
                                         int pg, int jg) {
    const float* wp = W + 4 * jg;
    const int p0 = 2 * pg, p1 = p0 + 1;
    float acc[2][4];
#pragma unroll
    for (int pi = 0; pi < 2; ++pi) {
        acc[pi][0] = bias.x; acc[pi][1] = bias.y;
        acc[pi][2] = bias.z; acc[pi][3] = bias.w;
    }
    float4 wbuf[4][4];   // [stage][k-row]
    float4 hbuf[4][2];   // [stage][path]
#pragma unroll
    for (int s = 0; s < 3; ++s) {
        const int k = 4 * s;
#pragma unroll
        for (int r = 0; r < 4; ++r) wbuf[s][r] = ldg4(wp + (k + r) * HH);
        hbuf[s][0] = *(const float4*)&hin[p0][k];
        hbuf[s][1] = *(const float4*)&hin[p1][k];
    }
#pragma unroll 4
    for (int kc = 0; kc < 64; ++kc) {
        // prefetch chunk kc+3 into stage (kc+3)&3 (clamped redundant reload at tail)
        const int sp = (kc + 3) & 3;
        const int kp = (kc + 3 < 64) ? (kc + 3) * 4 : 252;
#pragma unroll
        for (int r = 0; r < 4; ++r) wbuf[sp][r] = ldg4(wp + (kp + r) * HH);
        hbuf[sp][0] = *(const float4*)&hin[p0][kp];
        hbuf[sp][1] = *(const float4*)&hin[p1][kp];
        // consume stage kc&3
        const int s = kc & 3;
        const float4 w0 = wbuf[s][0], w1 = wbuf[s][1], w2 = wbuf[s][2], w3 = wbuf[s][3];
#pragma unroll
        for (int pi = 0; pi < 2; ++pi) {
            const float4 h = hbuf[s][pi];
            acc[pi][0] = fmaf(h.x, w0.x, acc[pi][0]); acc[pi][1] = fmaf(h.x, w0.y, acc[pi][1]);
            acc[pi][2] = fmaf(h.x, w0.z, acc[pi][2]); acc[pi][3] = fmaf(h.x, w0.w, acc[pi][3]);
            acc[pi][0] = fmaf(h.y, w1.x, acc[pi][0]); acc[pi][1] = fmaf(h.y, w1.y, acc[pi][1]);
            acc[pi][2] = fmaf(h.y, w1.z, acc[pi][2]); acc[pi][3] = fmaf(h.y, w1.w, acc[pi][3]);
            acc[pi][0] = fmaf(h.z, w2.x, acc[pi][0]); acc[pi][1] = fmaf(h.z, w2.y, acc[pi][1]);
            acc[pi][2] = fmaf(h.z, w2.z, acc[pi][2]); acc[pi][3] = fmaf(h.z, w2.w, acc[pi][3]);
            acc[pi][0] = fmaf(h.w, w3.x, acc[pi][0]); acc[pi][1] = fmaf(h.w, w3.y, acc[pi][1]);
            acc[pi][2] = fmaf(h.w, w3.z, acc[pi][2]); acc[pi][3] = fmaf(h.w, w3.w, acc[pi][3]);
        }
    }
#pragma unroll
    for (int pi = 0; pi < 2; ++pi) {
        float4 o;
        o.x = acc[pi][0]; o.y = acc[pi][1]; o.z = acc[pi][2]; o.w = acc[pi][3];
        if (RELU) {
            o.x = fmaxf(o.x, 0.0f); o.y = fmaxf(o.y, 0.0f);
            o.z = fmaxf(o.z, 0.0f); o.w = fmaxf(o.w, 0.0f);
        }
        *(float4*)&hout[2 * pg + pi][4 * jg] = o;
    }
}

// 8->256 dense + bias + relu. Tile 2 paths x 4 cols. W0 is 8KB -> L1-resident.
__device__ __forceinline__ void dense8(const float* __restrict__ W0,
                                       const float4 bias,
                                       const float (&x)[PB][8],
                                       float (&hout)[PB][SS],
                                       int pg, int jg) {
    const float* wp = W0 + 4 * jg;
    const int p0 = 2 * pg, p1 = p0 + 1;
    float4 w[8];
#pragma unroll
    for (int k = 0; k < 8; ++k) w[k] = ldg4(wp + k * HH);
    float acc[2][4];
#pragma unroll
    for (int pi = 0; pi < 2; ++pi) {
        const float* xr = x[p0 + pi];
        float a0 = bias.x, a1 = bias.y, a2 = bias.z, a3 = bias.w;
#pragma unroll
        for (int k = 0; k < 8; ++k) {
            const float xv = xr[k];
            a0 = fmaf(xv, w[k].x, a0); a1 = fmaf(xv, w[k].y, a1);
            a2 = fmaf(xv, w[k].z, a2); a3 = fmaf(xv, w[k].w, a3);
        }
        float4 o;
        o.x = fmaxf(a0, 0.0f); o.y = fmaxf(a1, 0.0f);
        o.z = fmaxf(a2, 0.0f); o.w = fmaxf(a3, 0.0f);
        *(float4*)&hout[p0 + pi][4 * jg] = o;
    }
    (void)acc;
}

__global__ __launch_bounds__(256, 2)
void lv_kernel(const float* __restrict__ W0, const float* __restrict__ b0,
               const float* __restrict__ W1, const float* __restrict__ b1,
               const float* __restrict__ W2, const float* __restrict__ b2,
               const float* __restrict__ W3, const float* __restrict__ b3,
               const float* __restrict__ obs_init, const float* __restrict__ feature_init,
               const float* __restrict__ tn_store, const float* __restrict__ x1_store,
               const float* __restrict__ x2_store, const float* __restrict__ path_seed,
               float* __restrict__ out) {
    __shared__ float hA[PB][SS];
    __shared__ float hB[PB][SS];
    __shared__ float w3t[5][SS];   // W3 transposed: w3t[c][k]
    __shared__ float xs[PB][8];
    __shared__ float o3[PB][5];
    __shared__ float st[PB][2];

    const int tid = threadIdx.x;
    const int pg = tid & 3;        // path group: paths {2pg, 2pg+1}
    const int jg = tid >> 2;       // col group 0..63 -> cols 4*jg..4*jg+3
    const int pbase = blockIdx.x * PB;

    const float DTf = 0.1f;
    const float SQ = 0.31622776601683794f;  // sqrt(0.1)

    float* __restrict__ path_out = out;                          // (P, 2, 101)
    float* __restrict__ mu_out = out + PP * 2 * (LT + 1);        // (P*100, 2)
    float* __restrict__ sg_out = mu_out + PP * LT * 2;           // (P*100, 2, 2)

    float tval = feature_init[0];  // t0 = feature_init[0,0,0]

    // hoisted biases (step-invariant)
    const float4 bv0 = ldg4(b0 + 4 * jg);
    const float4 bv1 = ldg4(b1 + 4 * jg);
    const float4 bv2 = ldg4(b2 + 4 * jg);

    // layer-3 thread roles (wave 0 only)
    const int l3p = tid / 5, l3c = tid % 5;
    const float b3v = (tid < 40) ? b3[l3c] : 0.0f;

    // stage W3 transposed into LDS (once)
    for (int e = tid; e < HH * 5; e += 256) {
        const int k = e / 5, c = e % 5;
        w3t[c][k] = W3[e];
    }
    if (tid < PB) {
        const int p = tid, gp = pbase + p;
        st[p][0] = obs_init[gp * 2 + 0];
        st[p][1] = obs_init[gp * 2 + 1];
    }
    __syncthreads();

    for (int t = 0; t < LT; ++t) {
        if (t > 0) tval += DTf;  // matches ref's sequential fp32 accumulation
        if (tid < PB) {
            const int p = tid, gp = pbase + p;
            xs[p][0] = st[p][0];
            xs[p][1] = st[p][1];
            if (t == 0) {
#pragma unroll
                for (int f = 0; f < 6; ++f) xs[p][2 + f] = feature_init[gp * 6 + f];
                path_out[gp * 202 + 0] = obs_init[gp * 2 + 0];
                path_out[gp * 202 + 101] = obs_init[gp * 2 + 1];
            } else {
                const float tn = tn_store[t - 1];
                const float a1 = x1_store[t - 1];
                const float a2 = x2_store[t - 1];
                xs[p][2] = tval; xs[p][3] = tn;
                xs[p][4] = a1;   xs[p][5] = a2;
                xs[p][6] = a1;   xs[p][7] = a2;
            }
        }
        __syncthreads();                           // A: xs ready (also gates hA overwrite)

        dense8(W0, bv0, xs, hA, pg, jg);           // h0 = relu(x @ W0 + b0)
        __syncthreads();                           // B
        dense256<true>(W1, bv1, hA, hB, pg, jg);   // h1 = relu(h0 @ W1 + b1)
        __syncthreads();                           // C
        dense256<true>(W2, bv2, hB, hA, pg, jg);   // h2 = relu(h1 @ W2 + b2)
        __syncthreads();                           // D

        // layer 3: 256->5, threads 0..39 (one (path, col) each), W3 from LDS
        if (tid < 40) {
            float a = b3v;
            const float* hr = hA[l3p];
            const float* wr = w3t[l3c];
#pragma unroll 4
            for (int k4 = 0; k4 < 64; ++k4) {
                const float4 h = *(const float4*)&hr[4 * k4];
                const float4 w = *(const float4*)&wr[4 * k4];
                a = fmaf(h.x, w.x, a);
                a = fmaf(h.y, w.y, a);
                a = fmaf(h.z, w.z, a);
                a = fmaf(h.w, w.w, a);
            }
            o3[l3p][l3c] = a;
        }
        __syncthreads();                           // E: o3 ready

        // sampling + stores: threads 0..7, one path each. st/o3 producer-consumer
        // ordering for next step is covered by barrier A.
        if (tid < PB) {
            const int p = tid, gp = pbase + p;
            const float mu0 = o3[p][0];
            const float mu1 = o3[p][1];
            const float s11 = softplus_f(o3[p][2]);
            const float s21 = o3[p][3];
            const float s22 = softplus_f(o3[p][4]);
            const float e0 = path_seed[(size_t)t * PP * 2 + gp * 2 + 0];
            const float e1 = path_seed[(size_t)t * PP * 2 + gp * 2 + 1];
            const float n0 = softplus_f(st[p][0] + DTf * mu0 + SQ * (s11 * e0));
            const float n1 = softplus_f(st[p][1] + DTf * mu1 + SQ * (s21 * e0 + s22 * e1));
            st[p][0] = n0;
            st[p][1] = n1;
            path_out[gp * 202 + (t + 1)] = n0;
            path_out[gp * 202 + 101 + (t + 1)] = n1;
            mu_out[gp * 200 + t * 2 + 0] = mu0;
            mu_out[gp * 200 + t * 2 + 1] = mu1;
            sg_out[gp * 400 + t * 4 + 0] = s11;
            sg_out[gp * 400 + t * 4 + 1] = 0.0f;
            sg_out[gp * 400 + t * 4 + 2] = s21;
            sg_out[gp * 400 + t * 4 + 3] = s22;
        }
    }
}

extern "C" void kernel_launch(void* const* d_in, const int* in_sizes, int n_in,
                              void* d_out, int out_size, void* d_ws, size_t ws_size,
                              hipStream_t stream) {
    (void)in_sizes; (void)n_in; (void)out_size; (void)d_ws; (void)ws_size;
    lv_kernel<<<PP / PB, 256, 0, stream>>>(
        (const float*)d_in[0], (const float*)d_in[1],
        (const float*)d_in[2], (const float*)d_in[3],
        (const float*)d_in[4], (const float*)d_in[5],
        (const float*)d_in[6], (const float*)d_in[7],
        (const float*)d_in[8], (const float*)d_in[9],
        (const float*)d_in[10], (const float*)d_in[11],
        (const float*)d_in[12], (const float*)d_in[13],
        (float*)d_out);
}

// Round 4
// 871.916 us; speedup vs baseline: 7.2198x; 5.3237x over previous
//
#include <hip/hip_runtime.h>
#include <math.h>

// LotkaVolterra neural-SDE rollout. P=4096, H=256, 100 sequential steps.
// R4: bf16 MFMA (16x16x32) for the two 256x256 layers + layer 3.
// - Prologue kernel converts W1/W2/W3 to bf16 in exact B-fragment order into
//   d_ws (runs every launch; graph-safe). B-frag = one global_load_dwordx4.
// - h ping-pongs in LDS as bf16, row-major stride 264 (528B = odd multiple of
//   16B -> A-frag ds_read_b128 spreads banks; epilogue b16 writes <=4-way).
// - Block = 16 paths (MFMA M=16), 512 threads (8 waves), grid 256 (1/CU).
//   Wave w owns output col-groups {2w, 2w+1} (16 cols each) per 256-layer.
// - Layer 3 (256->5) via MFMA with W3 zero-padded to 16 cols, computed
//   redundantly by all waves (8 MFMAs), wave 0 writes o3 + samples (no extra
//   barrier: producer and consumer are both wave 0).

#define PP 4096
#define HH 256
#define LT 100
#define PB 16
#define SH 264          // bf16 LDS row stride: 528 B = 33*16B
#define NT 512

typedef __attribute__((ext_vector_type(8))) short short8;
typedef __attribute__((ext_vector_type(4))) float float4v;

__device__ __forceinline__ float softplus_f(float x) {
    return fmaxf(x, 0.0f) + log1pf(expf(-fabsf(x)));
}
__device__ __forceinline__ unsigned short f2bf(float f) {   // RNE fp32->bf16
    unsigned int u = __float_as_uint(f);
    u += 0x7fffu + ((u >> 16) & 1u);
    return (unsigned short)(u >> 16);
}
__device__ __forceinline__ float4 ldg4(const float* p) { return *(const float4*)p; }

// ---- prologue: pack weights as bf16 MFMA B-fragments into d_ws ----
// Wt1 [0,65536): idx = ((cg*8+ks)*64+lane)*8+j  <- W1[(ks*32+quad*8+j)*256 + cg*16+(lane&15)]
// Wt2 [65536,131072): same from W2
// Wt3 [131072,135168): idx = (ks*64+lane)*8+j <- W3[k*5+n] for n<5 else 0
__global__ void prep_weights(const float* __restrict__ W1, const float* __restrict__ W2,
                             const float* __restrict__ W3, unsigned short* __restrict__ wt) {
    const int i = blockIdx.x * 256 + threadIdx.x;
    if (i < 131072) {
        const int ii = i & 65535;
        const int j = ii & 7, lane = (ii >> 3) & 63, ks = (ii >> 9) & 7, cg = ii >> 12;
        const int k = ks * 32 + (lane >> 4) * 8 + j;
        const int n = cg * 16 + (lane & 15);
        const float* W = (i < 65536) ? W1 : W2;
        wt[i] = f2bf(W[k * 256 + n]);
    } else if (i < 135168) {
        const int ii = i - 131072;
        const int j = ii & 7, lane = (ii >> 3) & 63, ks = ii >> 9;
        const int k = ks * 32 + (lane >> 4) * 8 + j;
        const int n = lane & 15;
        wt[i] = (n < 5) ? f2bf(W3[k * 5 + n]) : (unsigned short)0;
    }
}

// 256->256 bf16 MFMA layer + bias + relu. hin/hout: bf16 LDS [PB][SH].
__device__ __forceinline__ void mfma256(const unsigned short* __restrict__ Wt,
                                        const unsigned short* __restrict__ hin,
                                        unsigned short* __restrict__ hout,
                                        float bv0, float bv1, int wv, int lane) {
    const int quad = lane >> 4, col = lane & 15;
    float4v acc0 = {bv0, bv0, bv0, bv0};
    float4v acc1 = {bv1, bv1, bv1, bv1};
    const unsigned short* arow = hin + col * SH;          // A: m = lane&15 (path)
    const unsigned short* w0p = Wt + ((wv * 2 + 0) * 8) * 512;  // (cg*8+ks)*64*8
    const unsigned short* w1p = Wt + ((wv * 2 + 1) * 8) * 512;
#pragma unroll
    for (int ks = 0; ks < 8; ++ks) {
        short8 a  = *(const short8*)(arow + ks * 32 + quad * 8);
        short8 b0 = *(const short8*)(w0p + (ks * 64 + lane) * 8);
        short8 b1 = *(const short8*)(w1p + (ks * 64 + lane) * 8);
        acc0 = __builtin_amdgcn_mfma_f32_16x16x32_bf16(a, b0, acc0, 0, 0, 0);
        acc1 = __builtin_amdgcn_mfma_f32_16x16x32_bf16(a, b1, acc1, 0, 0, 0);
    }
    // C/D layout: col = lane&15, row p = quad*4 + reg (m89-verified)
#pragma unroll
    for (int r = 0; r < 4; ++r) {
        const int p = quad * 4 + r;
        hout[p * SH + (wv * 2 + 0) * 16 + col] = f2bf(fmaxf(acc0[r], 0.0f));
        hout[p * SH + (wv * 2 + 1) * 16 + col] = f2bf(fmaxf(acc1[r], 0.0f));
    }
}

__global__ __launch_bounds__(NT, 1)
void lv_kernel(const float* __restrict__ W0, const float* __restrict__ b0,
               const float* __restrict__ b1, const float* __restrict__ b2,
               const float* __restrict__ b3,
               const float* __restrict__ obs_init, const float* __restrict__ feature_init,
               const float* __restrict__ tn_store, const float* __restrict__ x1_store,
               const float* __restrict__ x2_store, const float* __restrict__ path_seed,
               const unsigned short* __restrict__ wt,
               float* __restrict__ out) {
    __shared__ unsigned short hA[PB * SH];
    __shared__ unsigned short hB[PB * SH];
    __shared__ float xs[PB][8];
    __shared__ float o3[PB][5];
    __shared__ float st[PB][2];

    const int tid = threadIdx.x;
    const int lane = tid & 63;
    const int wv = tid >> 6;            // wave 0..7
    const int quad = lane >> 4;
    const int col = lane & 15;
    const int pbase = blockIdx.x * PB;

    const float DTf = 0.1f;
    const float SQ = 0.31622776601683794f;  // sqrt(0.1)

    const unsigned short* Wt1 = wt;
    const unsigned short* Wt2 = wt + 65536;
    const unsigned short* Wt3 = wt + 131072;

    float* __restrict__ path_out = out;                          // (P, 2, 101)
    float* __restrict__ mu_out = out + PP * 2 * (LT + 1);        // (P*100, 2)
    float* __restrict__ sg_out = mu_out + PP * LT * 2;           // (P*100, 2, 2)

    float tval = feature_init[0];  // t0

    // step-invariant hoists
    const float bv1a = b1[(wv * 2 + 0) * 16 + col];
    const float bv1b = b1[(wv * 2 + 1) * 16 + col];
    const float bv2a = b2[(wv * 2 + 0) * 16 + col];
    const float bv2b = b2[(wv * 2 + 1) * 16 + col];
    const float b3c = (col < 5) ? b3[col] : 0.0f;

    // layer-0 thread roles: p = tid>>5 (16 paths), 8 cols starting at c0
    const int l0p = tid >> 5;
    const int c0 = (tid & 31) * 8;
    const float4 b0a = ldg4(b0 + c0);
    const float4 b0b = ldg4(b0 + c0 + 4);

    if (tid < PB) {
        const int p = tid, gp = pbase + p;
        st[p][0] = obs_init[gp * 2 + 0];
        st[p][1] = obs_init[gp * 2 + 1];
    }

    for (int t = 0; t < LT; ++t) {
        if (t > 0) tval += DTf;
        if (tid < PB) {
            const int p = tid, gp = pbase + p;
            xs[p][0] = st[p][0];
            xs[p][1] = st[p][1];
            if (t == 0) {
#pragma unroll
                for (int f = 0; f < 6; ++f) xs[p][2 + f] = feature_init[gp * 6 + f];
                path_out[gp * 202 + 0] = obs_init[gp * 2 + 0];
                path_out[gp * 202 + 101] = obs_init[gp * 2 + 1];
            } else {
                const float tn = tn_store[t - 1];
                const float a1 = x1_store[t - 1];
                const float a2 = x2_store[t - 1];
                xs[p][2] = tval; xs[p][3] = tn;
                xs[p][4] = a1;   xs[p][5] = a2;
                xs[p][6] = a1;   xs[p][7] = a2;
            }
        }
        __syncthreads();                       // A: xs ready; hA free (L3 readers done)

        // ---- layer 0: 8->256, fp32 VALU, write bf16 into hA ----
        {
            const float4 xa = *(const float4*)&xs[l0p][0];
            const float4 xb = *(const float4*)&xs[l0p][4];
            const float xk[8] = {xa.x, xa.y, xa.z, xa.w, xb.x, xb.y, xb.z, xb.w};
            float a[8] = {b0a.x, b0a.y, b0a.z, b0a.w, b0b.x, b0b.y, b0b.z, b0b.w};
#pragma unroll
            for (int k = 0; k < 8; ++k) {
                const float4 wA = ldg4(W0 + k * HH + c0);
                const float4 wB = ldg4(W0 + k * HH + c0 + 4);
                const float xv = xk[k];
                a[0] = fmaf(xv, wA.x, a[0]); a[1] = fmaf(xv, wA.y, a[1]);
                a[2] = fmaf(xv, wA.z, a[2]); a[3] = fmaf(xv, wA.w, a[3]);
                a[4] = fmaf(xv, wB.x, a[4]); a[5] = fmaf(xv, wB.y, a[5]);
                a[6] = fmaf(xv, wB.z, a[6]); a[7] = fmaf(xv, wB.w, a[7]);
            }
            short8 o;
#pragma unroll
            for (int c = 0; c < 8; ++c) o[c] = (short)f2bf(fmaxf(a[c], 0.0f));
            *(short8*)&hA[l0p * SH + c0] = o;
        }
        __syncthreads();                       // B: h0 ready

        mfma256(Wt1, hA, hB, bv1a, bv1b, wv, lane);   // h1 = relu(h0 @ W1 + b1)
        __syncthreads();                       // C: h1 ready, hA dead
        mfma256(Wt2, hB, hA, bv2a, bv2b, wv, lane);   // h2 = relu(h1 @ W2 + b2)
        __syncthreads();                       // D: h2 ready

        // ---- layer 3: 256->5 via MFMA (W3 padded to 16 cols), all waves redundant ----
        {
            float4v acc = {b3c, b3c, b3c, b3c};
            const unsigned short* arow = hA + col * SH;
#pragma unroll
            for (int ks = 0; ks < 8; ++ks) {
                short8 a = *(const short8*)(arow + ks * 32 + quad * 8);
                short8 b = *(const short8*)(Wt3 + (ks * 64 + lane) * 8);
                acc = __builtin_amdgcn_mfma_f32_16x16x32_bf16(a, b, acc, 0, 0, 0);
            }
            if (wv == 0 && col < 5) {
#pragma unroll
                for (int r = 0; r < 4; ++r) o3[quad * 4 + r][col] = acc[r];
            }
        }
        // o3 produced and consumed within wave 0 -> no barrier needed

        if (tid < PB) {
            const int p = tid, gp = pbase + p;
            const float mu0 = o3[p][0];
            const float mu1 = o3[p][1];
            const float s11 = softplus_f(o3[p][2]);
            const float s21 = o3[p][3];
            const float s22 = softplus_f(o3[p][4]);
            const float e0 = path_seed[(size_t)t * PP * 2 + gp * 2 + 0];
            const float e1 = path_seed[(size_t)t * PP * 2 + gp * 2 + 1];
            const float n0 = softplus_f(st[p][0] + DTf * mu0 + SQ * (s11 * e0));
            const float n1 = softplus_f(st[p][1] + DTf * mu1 + SQ * (s21 * e0 + s22 * e1));
            st[p][0] = n0;
            st[p][1] = n1;
            path_out[gp * 202 + (t + 1)] = n0;
            path_out[gp * 202 + 101 + (t + 1)] = n1;
            mu_out[gp * 200 + t * 2 + 0] = mu0;
            mu_out[gp * 200 + t * 2 + 1] = mu1;
            sg_out[gp * 400 + t * 4 + 0] = s11;
            sg_out[gp * 400 + t * 4 + 1] = 0.0f;
            sg_out[gp * 400 + t * 4 + 2] = s21;
            sg_out[gp * 400 + t * 4 + 3] = s22;
        }
        // next-iteration barrier A gates hA overwrite and st/xs visibility
    }
}

extern "C" void kernel_launch(void* const* d_in, const int* in_sizes, int n_in,
                              void* d_out, int out_size, void* d_ws, size_t ws_size,
                              hipStream_t stream) {
    (void)in_sizes; (void)n_in; (void)out_size; (void)ws_size;
    unsigned short* wt = (unsigned short*)d_ws;   // 135168 bf16 = 264 KB
    prep_weights<<<528, 256, 0, stream>>>(
        (const float*)d_in[2],   // W1
        (const float*)d_in[4],   // W2
        (const float*)d_in[6],   // W3
        wt);
    lv_kernel<<<PP / PB, NT, 0, stream>>>(
        (const float*)d_in[0],   // W0
        (const float*)d_in[1],   // b0
        (const float*)d_in[3],   // b1
        (const float*)d_in[5],   // b2
        (const float*)d_in[7],   // b3
        (const float*)d_in[8],   // obs_init
        (const float*)d_in[9],   // feature_init
        (const float*)d_in[10],  // tn_store
        (const float*)d_in[11],  // x1_store
        (const float*)d_in[12],  // x2_store
        (const float*)d_in[13],  // path_seed
        wt,
        (float*)d_out);
}

// Round 5
// 520.480 us; speedup vs baseline: 12.0948x; 1.6752x over previous
//
#include <hip/hip_runtime.h>
#include <math.h>

// LotkaVolterra neural-SDE rollout. P=4096, H=256, 100 sequential steps.
// R5 (on top of R4's bf16-MFMA structure):
//  - W1/W2 bf16 B-fragments held in VGPRs per wave (128 VGPRs), loaded once
//    before the time loop -> K-loop is ds_read_b128 + 2 MFMA, no global loads.
//  - W3 fragments staged to LDS once; layer-3 computed by wave 0 only.
//  - ALL outputs buffered in LDS (pbuf/mbuf/sbuf, 51 KB) and written once,
//    coalesced float4, after the loop. No global stores inside the step loop
//    -> __syncthreads no longer drains scattered HBM write-allocate traffic.
//  - Seeds + next-step scalar features prefetched at loop top.
// Block = 16 paths, 512 threads (8 waves, 2/SIMD), grid 256 (1 block/CU).

#define PP 4096
#define HH 256
#define LT 100
#define PB 16
#define SH 264          // bf16 LDS row stride: 528 B
#define NT 512

typedef __attribute__((ext_vector_type(8))) short short8;
typedef __attribute__((ext_vector_type(4))) float float4v;

__device__ __forceinline__ float softplus_f(float x) {
    return fmaxf(x, 0.0f) + log1pf(expf(-fabsf(x)));
}
__device__ __forceinline__ unsigned short f2bf(float f) {   // RNE fp32->bf16
    unsigned int u = __float_as_uint(f);
    u += 0x7fffu + ((u >> 16) & 1u);
    return (unsigned short)(u >> 16);
}
__device__ __forceinline__ float4 ldg4(const float* p) { return *(const float4*)p; }

// ---- prologue: pack weights as bf16 MFMA B-fragments into d_ws ----
// Wt1 [0,65536): idx = ((cg*8+ks)*64+lane)*8+j  <- W1[(ks*32+quad*8+j)*256 + cg*16+(lane&15)]
// Wt2 [65536,131072): same from W2
// Wt3 [131072,135168): idx = (ks*64+lane)*8+j <- W3[k*5+n] for n<5 else 0
__global__ void prep_weights(const float* __restrict__ W1, const float* __restrict__ W2,
                             const float* __restrict__ W3, unsigned short* __restrict__ wt) {
    const int i = blockIdx.x * 256 + threadIdx.x;
    if (i < 131072) {
        const int ii = i & 65535;
        const int j = ii & 7, lane = (ii >> 3) & 63, ks = (ii >> 9) & 7, cg = ii >> 12;
        const int k = ks * 32 + (lane >> 4) * 8 + j;
        const int n = cg * 16 + (lane & 15);
        const float* W = (i < 65536) ? W1 : W2;
        wt[i] = f2bf(W[k * 256 + n]);
    } else if (i < 135168) {
        const int ii = i - 131072;
        const int j = ii & 7, lane = (ii >> 3) & 63, ks = ii >> 9;
        const int k = ks * 32 + (lane >> 4) * 8 + j;
        const int n = lane & 15;
        wt[i] = (n < 5) ? f2bf(W3[k * 5 + n]) : (unsigned short)0;
    }
}

// 256->256 bf16 MFMA layer, B-fragments from registers.
__device__ __forceinline__ void mfma256_reg(const short8 (&wf)[16],
                                            const unsigned short* __restrict__ hin,
                                            unsigned short* __restrict__ hout,
                                            float bv0, float bv1, int wv, int lane) {
    const int quad = lane >> 4, col = lane & 15;
    float4v acc0 = {bv0, bv0, bv0, bv0};
    float4v acc1 = {bv1, bv1, bv1, bv1};
    const unsigned short* arow = hin + col * SH;          // A: m = lane&15 (path)
#pragma unroll
    for (int ks = 0; ks < 8; ++ks) {
        short8 a = *(const short8*)(arow + ks * 32 + quad * 8);
        acc0 = __builtin_amdgcn_mfma_f32_16x16x32_bf16(a, wf[ks], acc0, 0, 0, 0);
        acc1 = __builtin_amdgcn_mfma_f32_16x16x32_bf16(a, wf[8 + ks], acc1, 0, 0, 0);
    }
    // C/D layout: col = lane&15, row p = quad*4 + reg (m89-verified)
#pragma unroll
    for (int r = 0; r < 4; ++r) {
        const int p = quad * 4 + r;
        hout[p * SH + (wv * 2 + 0) * 16 + col] = f2bf(fmaxf(acc0[r], 0.0f));
        hout[p * SH + (wv * 2 + 1) * 16 + col] = f2bf(fmaxf(acc1[r], 0.0f));
    }
}

__global__ __launch_bounds__(NT, 2)
void lv_kernel(const float* __restrict__ W0, const float* __restrict__ b0,
               const float* __restrict__ b1, const float* __restrict__ b2,
               const float* __restrict__ b3,
               const float* __restrict__ obs_init, const float* __restrict__ feature_init,
               const float* __restrict__ tn_store, const float* __restrict__ x1_store,
               const float* __restrict__ x2_store, const float* __restrict__ path_seed,
               const unsigned short* __restrict__ wt,
               float* __restrict__ out) {
    __shared__ unsigned short hA[PB * SH];
    __shared__ unsigned short hB[PB * SH];
    __shared__ __align__(16) unsigned short w3l[4096];   // W3 fragments
    __shared__ float xs[PB][8];
    __shared__ float o3[PB][5];
    __shared__ __align__(16) float pbuf[PB * 202];       // path output buffer
    __shared__ __align__(16) float mbuf[PB * 200];       // mu output buffer
    __shared__ __align__(16) float sbuf[PB * 400];       // sigma output buffer

    const int tid = threadIdx.x;
    const int lane = tid & 63;
    const int wv = tid >> 6;            // wave 0..7
    const int quad = lane >> 4;
    const int col = lane & 15;
    const int pbase = blockIdx.x * PB;

    const float DTf = 0.1f;
    const float SQ = 0.31622776601683794f;  // sqrt(0.1)

    const unsigned short* Wt1 = wt;
    const unsigned short* Wt2 = wt + 65536;
    const unsigned short* Wt3 = wt + 131072;

    // ---- per-wave weight fragments into registers (once) ----
    short8 wf1[16], wf2[16];
#pragma unroll
    for (int cg2 = 0; cg2 < 2; ++cg2) {
#pragma unroll
        for (int ks = 0; ks < 8; ++ks) {
            const int idx = (((wv * 2 + cg2) * 8 + ks) * 64 + lane) * 8;
            wf1[cg2 * 8 + ks] = *(const short8*)(Wt1 + idx);
            wf2[cg2 * 8 + ks] = *(const short8*)(Wt2 + idx);
        }
    }
    // stage W3 fragments into LDS (8192 B, one float4 per thread)
    ((float4*)w3l)[tid] = ((const float4*)Wt3)[tid];

    // step-invariant hoists
    const float bv1a = b1[(wv * 2 + 0) * 16 + col];
    const float bv1b = b1[(wv * 2 + 1) * 16 + col];
    const float bv2a = b2[(wv * 2 + 0) * 16 + col];
    const float bv2b = b2[(wv * 2 + 1) * 16 + col];
    const float b3c = (col < 5) ? b3[col] : 0.0f;

    // layer-0 thread roles: p = tid>>5 (16 paths), 8 cols starting at c0
    const int l0p = tid >> 5;
    const int c0 = (tid & 31) * 8;
    const float4 b0a = ldg4(b0 + c0);
    const float4 b0b = ldg4(b0 + c0 + 4);

    float tval = feature_init[0];  // t0
    float st0 = 0.0f, st1 = 0.0f;  // per-path state, lanes 0..15 of wave 0

    if (tid < PB) {
        const int p = tid, gp = pbase + p;
        st0 = obs_init[gp * 2 + 0];
        st1 = obs_init[gp * 2 + 1];
        xs[p][0] = st0;
        xs[p][1] = st1;
#pragma unroll
        for (int f = 0; f < 6; ++f) xs[p][2 + f] = feature_init[gp * 6 + f];
        pbuf[p * 202 + 0] = st0;
        pbuf[p * 202 + 101] = st1;
    }
    __syncthreads();                          // weights/w3l/xs ready

    for (int t = 0; t < LT; ++t) {
        // prefetch this step's seeds + next step's scalar features (used ~3 barriers later)
        float e0 = 0.0f, e1 = 0.0f, ftn = 0.0f, fx1 = 0.0f, fx2 = 0.0f;
        if (tid < PB) {
            const int gp = pbase + tid;
            e0 = path_seed[(size_t)t * PP * 2 + gp * 2 + 0];
            e1 = path_seed[(size_t)t * PP * 2 + gp * 2 + 1];
            if (t < LT - 1) {
                ftn = tn_store[t];
                fx1 = x1_store[t];
                fx2 = x2_store[t];
            }
        }

        // ---- layer 0: 8->256, fp32 VALU, write bf16 into hA ----
        {
            const float4 xa = *(const float4*)&xs[l0p][0];
            const float4 xb = *(const float4*)&xs[l0p][4];
            const float xk[8] = {xa.x, xa.y, xa.z, xa.w, xb.x, xb.y, xb.z, xb.w};
            float a[8] = {b0a.x, b0a.y, b0a.z, b0a.w, b0b.x, b0b.y, b0b.z, b0b.w};
#pragma unroll
            for (int k = 0; k < 8; ++k) {
                const float4 wA = ldg4(W0 + k * HH + c0);
                const float4 wB = ldg4(W0 + k * HH + c0 + 4);
                const float xv = xk[k];
                a[0] = fmaf(xv, wA.x, a[0]); a[1] = fmaf(xv, wA.y, a[1]);
                a[2] = fmaf(xv, wA.z, a[2]); a[3] = fmaf(xv, wA.w, a[3]);
                a[4] = fmaf(xv, wB.x, a[4]); a[5] = fmaf(xv, wB.y, a[5]);
                a[6] = fmaf(xv, wB.z, a[6]); a[7] = fmaf(xv, wB.w, a[7]);
            }
            short8 o;
#pragma unroll
            for (int c = 0; c < 8; ++c) o[c] = (short)f2bf(fmaxf(a[c], 0.0f));
            *(short8*)&hA[l0p * SH + c0] = o;
        }
        __syncthreads();                       // B: h0 ready

        mfma256_reg(wf1, hA, hB, bv1a, bv1b, wv, lane);   // h1 = relu(h0 @ W1 + b1)
        __syncthreads();                       // C: h1 ready, hA dead
        mfma256_reg(wf2, hB, hA, bv2a, bv2b, wv, lane);   // h2 = relu(h1 @ W2 + b2)
        __syncthreads();                       // D: h2 ready

        // ---- layer 3 (wave 0 only): 256->5 via MFMA, W3 frags from LDS ----
        if (wv == 0) {
            float4v acc = {b3c, b3c, b3c, b3c};
            const unsigned short* arow = hA + col * SH;
#pragma unroll
            for (int ks = 0; ks < 8; ++ks) {
                short8 a = *(const short8*)(arow + ks * 32 + quad * 8);
                short8 b = *(const short8*)(w3l + (ks * 64 + lane) * 8);
                acc = __builtin_amdgcn_mfma_f32_16x16x32_bf16(a, b, acc, 0, 0, 0);
            }
            if (col < 5) {
#pragma unroll
                for (int r = 0; r < 4; ++r) o3[quad * 4 + r][col] = acc[r];
            }
            // o3 produced and consumed within wave 0 -> intra-wave lgkmcnt only

            if (tid < PB) {
                const int p = tid;
                const float mu0 = o3[p][0];
                const float mu1 = o3[p][1];
                const float s11 = softplus_f(o3[p][2]);
                const float s21 = o3[p][3];
                const float s22 = softplus_f(o3[p][4]);
                const float n0 = softplus_f(st0 + DTf * mu0 + SQ * (s11 * e0));
                const float n1 = softplus_f(st1 + DTf * mu1 + SQ * (s21 * e0 + s22 * e1));
                st0 = n0;
                st1 = n1;
                // outputs -> LDS buffers
                pbuf[p * 202 + (t + 1)] = n0;
                pbuf[p * 202 + 101 + (t + 1)] = n1;
                mbuf[p * 200 + t * 2 + 0] = mu0;
                mbuf[p * 200 + t * 2 + 1] = mu1;
                sbuf[p * 400 + t * 4 + 0] = s11;
                sbuf[p * 400 + t * 4 + 1] = 0.0f;
                sbuf[p * 400 + t * 4 + 2] = s21;
                sbuf[p * 400 + t * 4 + 3] = s22;
                // next step's input
                const float tnew = tval + DTf;
                xs[p][0] = n0; xs[p][1] = n1;
                xs[p][2] = tnew; xs[p][3] = ftn;
                xs[p][4] = fx1; xs[p][5] = fx2;
                xs[p][6] = fx1; xs[p][7] = fx2;
            }
        }
        tval += DTf;          // all lanes keep tval in lockstep (fp32 sequential, matches ref)
        __syncthreads();       // A: xs/st ready; hA free for next layer0
    }

    // ---- coalesced output write phase ----
    float* __restrict__ pdst = out + (size_t)pbase * 202;
    float* __restrict__ mdst = out + (size_t)PP * 202 + (size_t)pbase * 200;
    float* __restrict__ sdst = out + (size_t)PP * 202 + (size_t)PP * 200 + (size_t)pbase * 400;
    for (int i = tid; i < PB * 202 / 4; i += NT) ((float4*)pdst)[i] = ((const float4*)pbuf)[i];
    for (int i = tid; i < PB * 200 / 4; i += NT) ((float4*)mdst)[i] = ((const float4*)mbuf)[i];
    for (int i = tid; i < PB * 400 / 4; i += NT) ((float4*)sdst)[i] = ((const float4*)sbuf)[i];
}

extern "C" void kernel_launch(void* const* d_in, const int* in_sizes, int n_in,
                              void* d_out, int out_size, void* d_ws, size_t ws_size,
                              hipStream_t stream) {
    (void)in_sizes; (void)n_in; (void)out_size; (void)ws_size;
    unsigned short* wt = (unsigned short*)d_ws;   // 135168 bf16 = 264 KB
    prep_weights<<<528, 256, 0, stream>>>(
        (const float*)d_in[2],   // W1
        (const float*)d_in[4],   // W2
        (const float*)d_in[6],   // W3
        wt);
    lv_kernel<<<PP / PB, NT, 0, stream>>>(
        (const float*)d_in[0],   // W0
        (const float*)d_in[1],   // b0
        (const float*)d_in[3],   // b1
        (const float*)d_in[5],   // b2
        (const float*)d_in[7],   // b3
        (const float*)d_in[8],   // obs_init
        (const float*)d_in[9],   // feature_init
        (const float*)d_in[10],  // tn_store
        (const float*)d_in[11],  // x1_store
        (const float*)d_in[12],  // x2_store
        (const float*)d_in[13],  // path_seed
        wt,
        (float*)d_out);
}